// Round 4
// baseline (1270.982 us; speedup 1.0000x reference)
//
#include <hip/hip_runtime.h>
#include <hip/hip_bf16.h>
#include <stdint.h>

// Problem constants
#define B_ 64
#define T_ 512
#define H_ 256
#define D_ 512
#define MS_ 64
#define ML_ 8
#define NST_ 64

typedef unsigned short u16;
typedef unsigned int u32;
typedef __bf16 bf8 __attribute__((ext_vector_type(8)));
typedef float f4 __attribute__((ext_vector_type(4)));

__device__ __forceinline__ u16 f2bf(float f) {
    u32 u = __builtin_bit_cast(u32, f);
    u += 0x7fffu + ((u >> 16) & 1u);   // round-to-nearest-even
    return (u16)(u >> 16);
}
__device__ __forceinline__ float bf2f(u16 v) {
    u32 u = ((u32)v) << 16;
    return __builtin_bit_cast(float, u);
}
__device__ __forceinline__ float sigm(float x) { return 1.f / (1.f + __expf(-x)); }

// ---------------- weight packing ----------------
// wih2[2048][512] bf16 : rows 0..1023 = W_ih_f, 1024..2047 = W_ih_b
// whh2[2][1024][256] bf16
__global__ __launch_bounds__(256) void build_w2(const float* __restrict__ wihf,
                                                const float* __restrict__ whhf,
                                                const float* __restrict__ wihb,
                                                const float* __restrict__ whhb,
                                                u16* __restrict__ wih2,
                                                u16* __restrict__ whh2) {
    int i = blockIdx.x * 256 + threadIdx.x;
    if (i < 1048576) {
        int g = i >> 9, k = i & 511;
        float v = (g < 1024) ? wihf[g * 512 + k] : wihb[(g - 1024) * 512 + k];
        wih2[i] = f2bf(v);
    } else if (i < 1572864) {
        int j = i - 1048576;
        int dir = j >> 18;
        int r = j & 262143;
        int g = r >> 8, k = r & 255;
        float v = dir ? whhb[g * 256 + k] : whhf[g * 256 + k];
        whh2[j] = f2bf(v);
    }
}

__global__ __launch_bounds__(256) void zero_ws(uint4* __restrict__ dst, int n4) {
    int i = blockIdx.x * 256 + threadIdx.x;
    if (i < n4) { uint4 z = {0u, 0u, 0u, 0u}; dst[i] = z; }
}

// ---------------- span packing (parallel, 1 block/row, 1 thread/token) -------
__global__ __launch_bounds__(512) void pack_spans2(const int* __restrict__ bio,
                                                   int* __restrict__ tok,
                                                   int* __restrict__ lenb) {
    __shared__ int wsum[8];
    __shared__ int start_s[64];
    __shared__ int len_s[64];
    int b = blockIdx.x;
    int t = threadIdx.x;
    int lane = t & 63, w = t >> 6;
    int v = bio[b * T_ + t];
    int bm = (v == 1);
    int im = (v == 2);
    if (t < 64) len_s[t] = 0;

    int x = bm;
#pragma unroll
    for (int off = 1; off < 64; off <<= 1) {
        int y = __shfl_up(x, off, 64);
        if (lane >= off) x += y;
    }
    if (lane == 63) wsum[w] = x;
    __syncthreads();
    int wof = 0;
    for (int i = 0; i < w; ++i) wof += wsum[i];
    int sid = x + wof - 1;
    int valid = ((bm | im) && sid >= 0) ? 1 : 0;
    __syncthreads();

    x = valid;
#pragma unroll
    for (int off = 1; off < 64; off <<= 1) {
        int y = __shfl_up(x, off, 64);
        if (lane >= off) x += y;
    }
    if (lane == 63) wsum[w] = x;
    __syncthreads();
    wof = 0;
    for (int i = 0; i < w; ++i) wof += wsum[i];
    int cs = x + wof;

    if (bm && sid < MS_) start_s[sid] = cs;
    __syncthreads();

    if (valid && sid < MS_) {
        int rank = cs - start_s[sid];
        if (rank < ML_) {
            tok[(b * MS_ + sid) * ML_ + rank] = t;
            atomicAdd(&len_s[sid], 1);
        }
    }
    __syncthreads();
    if (t < 64) lenb[b * MS_ + t] = len_s[t];
}

// ---------------- aux lists: valid (span,rank) rows + length-sorted span order
__global__ __launch_bounds__(256) void build_aux(const int* __restrict__ lenb,
                                                 int* __restrict__ vrows,
                                                 int* __restrict__ sorder,
                                                 int* __restrict__ counts) {
    __shared__ int wsum[4];
    __shared__ int gbase;
    int tid = threadIdx.x;
    int lane = tid & 63, w = tid >> 6;
    int len[16];
#pragma unroll
    for (int i = 0; i < 16; ++i) len[i] = lenb[tid * 16 + i];

    // valid rows (span*8 + rank for rank < len)
    int cnt = 0;
#pragma unroll
    for (int i = 0; i < 16; ++i) cnt += len[i];
    int x = cnt;
#pragma unroll
    for (int off = 1; off < 64; off <<= 1) {
        int y = __shfl_up(x, off, 64);
        if (lane >= off) x += y;
    }
    if (lane == 63) wsum[w] = x;
    __syncthreads();
    int wof = 0;
    for (int i = 0; i < w; ++i) wof += wsum[i];
    int pos = wof + x - cnt;
#pragma unroll
    for (int i = 0; i < 16; ++i)
        for (int r = 0; r < len[i]; ++r) vrows[pos++] = (tid * 16 + i) * 8 + r;
    if (tid == 255) counts[0] = pos;   // nv
    __syncthreads();

    // sorder: spans bucketed by descending length (stable)
    if (tid == 0) gbase = 0;
    __syncthreads();
    for (int L = 8; L >= 0; --L) {
        int c = 0;
#pragma unroll
        for (int i = 0; i < 16; ++i) c += (len[i] == L) ? 1 : 0;
        x = c;
#pragma unroll
        for (int off = 1; off < 64; off <<= 1) {
            int y = __shfl_up(x, off, 64);
            if (lane >= off) x += y;
        }
        if (lane == 63) wsum[w] = x;
        __syncthreads();
        wof = 0;
        for (int i = 0; i < w; ++i) wof += wsum[i];
        int p2 = gbase + wof + x - c;
#pragma unroll
        for (int i = 0; i < 16; ++i)
            if (len[i] == L) sorder[p2++] = tid * 16 + i;
        __syncthreads();
        if (tid == 255) gbase = p2;
        __syncthreads();
    }
}

// Gather-convert used tokens: xg[span*8+rank][512] bf16.
__global__ __launch_bounds__(64) void conv_gather(const float* __restrict__ repr,
                                                  const int* __restrict__ tok,
                                                  const int* __restrict__ lenb,
                                                  u16* __restrict__ xg) {
    int sr = blockIdx.x;
    int span = sr >> 3, rank = sr & 7;
    if (rank >= lenb[span]) return;
    int t = tok[sr];
    int b = span >> 6;
    const float4* src = (const float4*)(repr + (size_t)(b * T_ + t) * D_);
    ushort4* dst = (ushort4*)(xg + (size_t)sr * D_);
    int i = threadIdx.x;
    float4 v0 = src[i * 2], v1 = src[i * 2 + 1];
    ushort4 o0, o1;
    o0.x = f2bf(v0.x); o0.y = f2bf(v0.y); o0.z = f2bf(v0.z); o0.w = f2bf(v0.w);
    o1.x = f2bf(v1.x); o1.y = f2bf(v1.y); o1.z = f2bf(v1.z); o1.w = f2bf(v1.w);
    dst[i * 2] = o0; dst[i * 2 + 1] = o1;
}

// ---------------- input GEMM: xw[sr][2048] = x[sr] @ wih2^T + bias (bf16 out)
// 128x128 tiles, BK=64, only valid rows (vrows/nv), bias folded in epilogue.
__global__ __launch_bounds__(256) void xw_gemm(const u16* __restrict__ xg,
                                               const u16* __restrict__ wih2,
                                               const float* __restrict__ b_f,
                                               const float* __restrict__ b_b,
                                               const int* __restrict__ vrows,
                                               const int* __restrict__ counts,
                                               u16* __restrict__ xw) {
    int nv = counts[0];
    int base = blockIdx.y * 128;
    if (base >= nv) return;
    __shared__ int varr[128];
    __shared__ u16 As[128 * 72];
    __shared__ u16 Bs[128 * 72];
    int tid = threadIdx.x;
    if (tid < 128) varr[tid] = (base + tid < nv) ? vrows[base + tid] : -1;
    __syncthreads();
    int lane = tid & 63, wv = tid >> 6;
    int mr = lane & 15, q = lane >> 4, q8 = q * 8;
    int m0 = (wv >> 1) * 64, n0 = (wv & 1) * 64;
    int bx = blockIdx.x;

    f4 acc[4][4];
    f4 zed = {0.f, 0.f, 0.f, 0.f};
#pragma unroll
    for (int i = 0; i < 4; ++i)
#pragma unroll
        for (int j = 0; j < 4; ++j) acc[i][j] = zed;

    for (int kt = 0; kt < 8; ++kt) {
#pragma unroll
        for (int i = 0; i < 4; ++i) {
            int cch = tid + i * 256;
            int row = cch >> 3, cc = (cch & 7) * 8;
            int vr = varr[row];
            uint4 v = {0u, 0u, 0u, 0u};
            if (vr >= 0) v = *(const uint4*)(xg + (size_t)vr * 512 + kt * 64 + cc);
            *(uint4*)&As[row * 72 + cc] = v;
            uint4 wv4 = *(const uint4*)(wih2 + (size_t)(bx * 128 + row) * 512 + kt * 64 + cc);
            *(uint4*)&Bs[row * 72 + cc] = wv4;
        }
        __syncthreads();
#pragma unroll
        for (int kk = 0; kk < 64; kk += 32) {
            bf8 af[4], bgv[4];
#pragma unroll
            for (int i = 0; i < 4; ++i) af[i] = *(const bf8*)&As[(m0 + i * 16 + mr) * 72 + kk + q8];
#pragma unroll
            for (int j = 0; j < 4; ++j) bgv[j] = *(const bf8*)&Bs[(n0 + j * 16 + mr) * 72 + kk + q8];
#pragma unroll
            for (int i = 0; i < 4; ++i)
#pragma unroll
                for (int j = 0; j < 4; ++j)
                    acc[i][j] = __builtin_amdgcn_mfma_f32_16x16x32_bf16(af[i], bgv[j], acc[i][j], 0, 0, 0);
        }
        __syncthreads();
    }
#pragma unroll
    for (int j = 0; j < 4; ++j) {
        int n = bx * 128 + n0 + j * 16 + mr;
        float bias = (n < 1024) ? b_f[n] : b_b[n - 1024];
#pragma unroll
        for (int i = 0; i < 4; ++i)
#pragma unroll
            for (int r = 0; r < 4; ++r) {
                int m = m0 + i * 16 + q * 4 + r;
                int vr = varr[m];
                if (vr >= 0) xw[(size_t)vr * 2048 + n] = f2bf(acc[i][j][r] + bias);
            }
    }
}

// ---------------- fused LSTM recurrence: one kernel, all 8 steps ----------------
// Block = 1 wave, 16 spans (length-sorted slice), one direction.
// Per step: gates = W_hh(A, global/L2) x h(B, LDS) via MFMA; C-layout puts all 4
// gate types for a (span,hidden) in-lane -> cell math directly on accumulators.
// c in VGPRs, h in LDS (bf16), pooled f32 RMW to global (masked by p<len).
__global__ __launch_bounds__(64) void lstm_fused(const u16* __restrict__ whh2,
                                                 const u16* __restrict__ xw,
                                                 const int* __restrict__ sorder,
                                                 const int* __restrict__ lenb,
                                                 float* __restrict__ pooled) {
    __shared__ u16 Hs[16 * 264];
    __shared__ int sl[16], ll[16];
    int bid = blockIdx.x;
    int dir = bid >> 8, slice = bid & 255;
    int tid = threadIdx.x;
    if (tid < 16) {
        int s = sorder[slice * 16 + tid];
        sl[tid] = s;
        ll[tid] = lenb[s];
    }
    for (int i = tid; i < 16 * 264 / 2; i += 64) ((u32*)Hs)[i] = 0u;
    __syncthreads();
    int maxP = ll[0];             // sorted descending -> first is longest
    if (maxP == 0) return;

    int mr = tid & 15, q = tid >> 4, q8 = q * 8;
    int gspan = sl[mr], glen = ll[mr];
    const u16* wdir = whh2 + (size_t)dir * 262144;
    float* poolp = pooled + (size_t)gspan * 512 + dir * 256;

    float c[64];
#pragma unroll
    for (int i = 0; i < 64; ++i) c[i] = 0.f;

    for (int p = 0; p < maxP; ++p) {
        __syncthreads();          // prior h writes visible
        bf8 bg[8];
#pragma unroll
        for (int kk = 0; kk < 8; ++kk)
            bg[kk] = *(const bf8*)&Hs[mr * 264 + kk * 32 + q8];
        bool msk = (p < glen);
        int rk = dir ? (glen - 1 - p) : p;
        rk = rk < 0 ? 0 : rk;
        const u16* xwp = xw + (size_t)(gspan * 8 + rk) * 2048 + dir * 1024;

#pragma unroll
        for (int hb = 0; hb < 4; ++hb) {
#pragma unroll
            for (int s = 0; s < 4; ++s) {
                f4 acc[4];
#pragma unroll
                for (int t = 0; t < 4; ++t) {
                    const u16* wr = wdir + (size_t)(t * 256 + hb * 64 + s * 16 + mr) * 256;
                    f4 a = {0.f, 0.f, 0.f, 0.f};
#pragma unroll
                    for (int kk = 0; kk < 8; ++kk) {
                        bf8 af = *(const bf8*)(wr + kk * 32 + q8);
                        a = __builtin_amdgcn_mfma_f32_16x16x32_bf16(af, bg[kk], a, 0, 0, 0);
                    }
                    acc[t] = a;
                }
                int col = hb * 64 + s * 16 + q * 4;
                // xw adds: 4 consecutive gates (q*4+r) per gate-type -> 8B loads
                f4 xv[4];
#pragma unroll
                for (int t = 0; t < 4; ++t) {
                    ushort4 uv = *(const ushort4*)(xwp + t * 256 + col);
                    xv[t][0] = bf2f(uv.x); xv[t][1] = bf2f(uv.y);
                    xv[t][2] = bf2f(uv.z); xv[t][3] = bf2f(uv.w);
                }
                float hv[4];
#pragma unroll
                for (int r = 0; r < 4; ++r) {
                    float I = acc[0][r] + xv[0][r];
                    float F = acc[1][r] + xv[1][r];
                    float G = acc[2][r] + xv[2][r];
                    float O = acc[3][r] + xv[3][r];
                    int ci = hb * 16 + s * 4 + r;
                    float cn = sigm(F) * c[ci] + sigm(I) * tanhf(G);
                    c[ci] = cn;
                    hv[r] = sigm(O) * tanhf(cn);
                }
                u16* hp = &Hs[mr * 264 + col];
                hp[0] = f2bf(hv[0]); hp[1] = f2bf(hv[1]);
                hp[2] = f2bf(hv[2]); hp[3] = f2bf(hv[3]);
                if (msk) {
                    float4 pv = *(float4*)(poolp + col);
                    pv.x += hv[0]; pv.y += hv[1]; pv.z += hv[2]; pv.w += hv[3];
                    *(float4*)(poolp + col) = pv;
                }
            }
        }
    }
}

// ---------------- final scores: MFMA GEMM [4096x512] x [512x64] ----------------
__global__ __launch_bounds__(256) void scores_mfma(const float* __restrict__ pooled,
                                                   const float* __restrict__ emb,
                                                   float* __restrict__ out) {
    int g = blockIdx.x;
    int tid = threadIdx.x;
    __shared__ u16 As[64 * 72];
    __shared__ u16 Bs[64 * 72];
    int lane = tid & 63;
    int w16 = (tid >> 6) * 16;
    int mr = lane & 15;
    int q = lane >> 4;
    int q8 = q * 8;

    f4 acc[4];
    f4 zed = {0.f, 0.f, 0.f, 0.f};
#pragma unroll
    for (int i = 0; i < 4; ++i) acc[i] = zed;

    for (int kt = 0; kt < 8; ++kt) {
#pragma unroll
        for (int i = 0; i < 2; ++i) {
            int cch = tid + i * 256;
            int row = cch >> 3;
            int cc = (cch & 7) * 8;
            const float4* a = (const float4*)(pooled + (size_t)(g * 64 + row) * 512 + kt * 64 + cc);
            float4 v0 = a[0], v1 = a[1];
            ushort4 o0, o1;
            o0.x = f2bf(v0.x); o0.y = f2bf(v0.y); o0.z = f2bf(v0.z); o0.w = f2bf(v0.w);
            o1.x = f2bf(v1.x); o1.y = f2bf(v1.y); o1.z = f2bf(v1.z); o1.w = f2bf(v1.w);
            *(ushort4*)&As[row * 72 + cc] = o0;
            *(ushort4*)&As[row * 72 + cc + 4] = o1;
            const float4* b = (const float4*)(emb + (size_t)row * 512 + kt * 64 + cc);
            float4 w0 = b[0], w1 = b[1];
            ushort4 p0, p1;
            p0.x = f2bf(w0.x); p0.y = f2bf(w0.y); p0.z = f2bf(w0.z); p0.w = f2bf(w0.w);
            p1.x = f2bf(w1.x); p1.y = f2bf(w1.y); p1.z = f2bf(w1.z); p1.w = f2bf(w1.w);
            *(ushort4*)&Bs[row * 72 + cc] = p0;
            *(ushort4*)&Bs[row * 72 + cc + 4] = p1;
        }
        __syncthreads();
#pragma unroll
        for (int kk = 0; kk < 64; kk += 32) {
            bf8 af = *(const bf8*)&As[(w16 + mr) * 72 + kk + q8];
#pragma unroll
            for (int nt = 0; nt < 4; ++nt) {
                bf8 bgv = *(const bf8*)&Bs[(nt * 16 + mr) * 72 + kk + q8];
                acc[nt] = __builtin_amdgcn_mfma_f32_16x16x32_bf16(af, bgv, acc[nt], 0, 0, 0);
            }
        }
        __syncthreads();
    }
#pragma unroll
    for (int nt = 0; nt < 4; ++nt)
#pragma unroll
        for (int r = 0; r < 4; ++r) {
            int m = g * 64 + w16 + q * 4 + r;
            int n = nt * 16 + mr;
            out[(size_t)m * 64 + n] = acc[nt][r];
        }
}

// ---------------- launch ----------------

extern "C" void kernel_launch(void* const* d_in, const int* in_sizes, int n_in,
                              void* d_out, int out_size, void* d_ws, size_t ws_size,
                              hipStream_t stream) {
    const float* lstm_repr = (const float*)d_in[0];
    const float* W_ih_f = (const float*)d_in[1];
    const float* W_hh_f = (const float*)d_in[2];
    const float* b_f    = (const float*)d_in[3];
    const float* W_ih_b = (const float*)d_in[4];
    const float* W_hh_b = (const float*)d_in[5];
    const float* b_b    = (const float*)d_in[6];
    const float* slot_emb = (const float*)d_in[7];
    const int* bio      = (const int*)d_in[8];
    float* out = (float*)d_out;

    char* ws = (char*)d_ws;
    u16*  xg     = (u16*)(ws + 0);              // 4096*8*512 bf16   = 33,554,432
    u16*  wih2   = (u16*)(ws + 33554432);       // 2048*512 bf16     =  2,097,152
    u16*  whh2   = (u16*)(ws + 35651584);       // 2*1024*256 bf16   =  1,048,576
    int*  tok    = (int*)(ws + 36700160);       // 4096*8 i32        =    131,072
    int*  lenb   = (int*)(ws + 36831232);       // 4096 i32          =     16,384
    int*  vrows  = (int*)(ws + 36847616);       // 32768 i32         =    131,072
    int*  sorder = (int*)(ws + 36978688);       // 4096 i32          =     16,384
    int*  counts = (int*)(ws + 36995072);       // pad 256
    u16*  xw     = (u16*)(ws + 36995328);       // 32768*2048 bf16   = 134,217,728
    float* pooled= (float*)(ws + 171213056);    // 4096*512 f32      =  8,388,608 (zeroed)
    // total: 179,601,664 bytes

    build_w2<<<6144, 256, 0, stream>>>(W_ih_f, W_hh_f, W_ih_b, W_hh_b, wih2, whh2);
    pack_spans2<<<64, 512, 0, stream>>>(bio, tok, lenb);
    build_aux<<<1, 256, 0, stream>>>(lenb, vrows, sorder, counts);
    conv_gather<<<32768, 64, 0, stream>>>(lstm_repr, tok, lenb, xg);
    zero_ws<<<2048, 256, 0, stream>>>((uint4*)pooled, 524288);
    xw_gemm<<<dim3(16, 256), 256, 0, stream>>>(xg, wih2, b_f, b_b, vrows, counts, xw);
    lstm_fused<<<512, 64, 0, stream>>>(whh2, xw, sorder, lenb, pooled);
    scores_mfma<<<64, 256, 0, stream>>>(pooled, slot_emb, out);
}

// Round 5
// 418.263 us; speedup vs baseline: 3.0387x; 3.0387x over previous
//
#include <hip/hip_runtime.h>
#include <hip/hip_bf16.h>
#include <stdint.h>

// Problem constants
#define B_ 64
#define T_ 512
#define H_ 256
#define D_ 512
#define MS_ 64
#define ML_ 8
#define NST_ 64

typedef unsigned short u16;
typedef unsigned int u32;
typedef __bf16 bf8 __attribute__((ext_vector_type(8)));
typedef float f4 __attribute__((ext_vector_type(4)));

__device__ __forceinline__ u16 f2bf(float f) {
    u32 u = __builtin_bit_cast(u32, f);
    u += 0x7fffu + ((u >> 16) & 1u);   // round-to-nearest-even
    return (u16)(u >> 16);
}
__device__ __forceinline__ float bf2f(u16 v) {
    u32 u = ((u32)v) << 16;
    return __builtin_bit_cast(float, u);
}
__device__ __forceinline__ float sigm(float x) { return 1.f / (1.f + __expf(-x)); }

// ---------------- weight packing ----------------
// wih2[2048][512] bf16 : rows 0..1023 = W_ih_f, 1024..2047 = W_ih_b
// whh2[2][1024][256] bf16
__global__ __launch_bounds__(256) void build_w2(const float* __restrict__ wihf,
                                                const float* __restrict__ whhf,
                                                const float* __restrict__ wihb,
                                                const float* __restrict__ whhb,
                                                u16* __restrict__ wih2,
                                                u16* __restrict__ whh2) {
    int i = blockIdx.x * 256 + threadIdx.x;
    if (i < 1048576) {
        int g = i >> 9, k = i & 511;
        float v = (g < 1024) ? wihf[g * 512 + k] : wihb[(g - 1024) * 512 + k];
        wih2[i] = f2bf(v);
    } else if (i < 1572864) {
        int j = i - 1048576;
        int dir = j >> 18;
        int r = j & 262143;
        int g = r >> 8, k = r & 255;
        float v = dir ? whhb[g * 256 + k] : whhf[g * 256 + k];
        whh2[j] = f2bf(v);
    }
}

__global__ __launch_bounds__(256) void zero_ws(uint4* __restrict__ dst, int n4) {
    int i = blockIdx.x * 256 + threadIdx.x;
    if (i < n4) { uint4 z = {0u, 0u, 0u, 0u}; dst[i] = z; }
}

// ---------------- span packing (parallel, 1 block/row, 1 thread/token) -------
__global__ __launch_bounds__(512) void pack_spans2(const int* __restrict__ bio,
                                                   int* __restrict__ tok,
                                                   int* __restrict__ lenb) {
    __shared__ int wsum[8];
    __shared__ int start_s[64];
    __shared__ int len_s[64];
    int b = blockIdx.x;
    int t = threadIdx.x;
    int lane = t & 63, w = t >> 6;
    int v = bio[b * T_ + t];
    int bm = (v == 1);
    int im = (v == 2);
    if (t < 64) len_s[t] = 0;

    int x = bm;
#pragma unroll
    for (int off = 1; off < 64; off <<= 1) {
        int y = __shfl_up(x, off, 64);
        if (lane >= off) x += y;
    }
    if (lane == 63) wsum[w] = x;
    __syncthreads();
    int wof = 0;
    for (int i = 0; i < w; ++i) wof += wsum[i];
    int sid = x + wof - 1;
    int valid = ((bm | im) && sid >= 0) ? 1 : 0;
    __syncthreads();

    x = valid;
#pragma unroll
    for (int off = 1; off < 64; off <<= 1) {
        int y = __shfl_up(x, off, 64);
        if (lane >= off) x += y;
    }
    if (lane == 63) wsum[w] = x;
    __syncthreads();
    wof = 0;
    for (int i = 0; i < w; ++i) wof += wsum[i];
    int cs = x + wof;

    if (bm && sid < MS_) start_s[sid] = cs;
    __syncthreads();

    if (valid && sid < MS_) {
        int rank = cs - start_s[sid];
        if (rank < ML_) {
            tok[(b * MS_ + sid) * ML_ + rank] = t;
            atomicAdd(&len_s[sid], 1);
        }
    }
    __syncthreads();
    if (t < 64) lenb[b * MS_ + t] = len_s[t];
}

// ---------------- aux lists: valid (span,rank) rows + length-sorted span order
__global__ __launch_bounds__(256) void build_aux(const int* __restrict__ lenb,
                                                 int* __restrict__ vrows,
                                                 int* __restrict__ sorder,
                                                 int* __restrict__ counts) {
    __shared__ int wsum[4];
    __shared__ int gbase;
    int tid = threadIdx.x;
    int lane = tid & 63, w = tid >> 6;
    int len[16];
#pragma unroll
    for (int i = 0; i < 16; ++i) len[i] = lenb[tid * 16 + i];

    // valid rows (span*8 + rank for rank < len)
    int cnt = 0;
#pragma unroll
    for (int i = 0; i < 16; ++i) cnt += len[i];
    int x = cnt;
#pragma unroll
    for (int off = 1; off < 64; off <<= 1) {
        int y = __shfl_up(x, off, 64);
        if (lane >= off) x += y;
    }
    if (lane == 63) wsum[w] = x;
    __syncthreads();
    int wof = 0;
    for (int i = 0; i < w; ++i) wof += wsum[i];
    int pos = wof + x - cnt;
#pragma unroll
    for (int i = 0; i < 16; ++i)
        for (int r = 0; r < len[i]; ++r) vrows[pos++] = (tid * 16 + i) * 8 + r;
    if (tid == 255) counts[0] = pos;   // nv
    __syncthreads();

    // sorder: spans bucketed by descending length (stable)
    if (tid == 0) gbase = 0;
    __syncthreads();
    for (int L = 8; L >= 0; --L) {
        int c = 0;
#pragma unroll
        for (int i = 0; i < 16; ++i) c += (len[i] == L) ? 1 : 0;
        x = c;
#pragma unroll
        for (int off = 1; off < 64; off <<= 1) {
            int y = __shfl_up(x, off, 64);
            if (lane >= off) x += y;
        }
        if (lane == 63) wsum[w] = x;
        __syncthreads();
        wof = 0;
        for (int i = 0; i < w; ++i) wof += wsum[i];
        int p2 = gbase + wof + x - c;
#pragma unroll
        for (int i = 0; i < 16; ++i)
            if (len[i] == L) sorder[p2++] = tid * 16 + i;
        __syncthreads();
        if (tid == 255) gbase = p2;
        __syncthreads();
    }
}

// Gather-convert used tokens: xg[span*8+rank][512] bf16.
__global__ __launch_bounds__(64) void conv_gather(const float* __restrict__ repr,
                                                  const int* __restrict__ tok,
                                                  const int* __restrict__ lenb,
                                                  u16* __restrict__ xg) {
    int sr = blockIdx.x;
    int span = sr >> 3, rank = sr & 7;
    if (rank >= lenb[span]) return;
    int t = tok[sr];
    int b = span >> 6;
    const float4* src = (const float4*)(repr + (size_t)(b * T_ + t) * D_);
    ushort4* dst = (ushort4*)(xg + (size_t)sr * D_);
    int i = threadIdx.x;
    float4 v0 = src[i * 2], v1 = src[i * 2 + 1];
    ushort4 o0, o1;
    o0.x = f2bf(v0.x); o0.y = f2bf(v0.y); o0.z = f2bf(v0.z); o0.w = f2bf(v0.w);
    o1.x = f2bf(v1.x); o1.y = f2bf(v1.y); o1.z = f2bf(v1.z); o1.w = f2bf(v1.w);
    dst[i * 2] = o0; dst[i * 2 + 1] = o1;
}

// ---------------- input GEMM: xw[sr][2048] = x[sr] @ wih2^T + bias (bf16 out)
__global__ __launch_bounds__(256) void xw_gemm(const u16* __restrict__ xg,
                                               const u16* __restrict__ wih2,
                                               const float* __restrict__ b_f,
                                               const float* __restrict__ b_b,
                                               const int* __restrict__ vrows,
                                               const int* __restrict__ counts,
                                               u16* __restrict__ xw) {
    int nv = counts[0];
    int base = blockIdx.y * 128;
    if (base >= nv) return;
    __shared__ int varr[128];
    __shared__ u16 As[128 * 72];
    __shared__ u16 Bs[128 * 72];
    int tid = threadIdx.x;
    if (tid < 128) varr[tid] = (base + tid < nv) ? vrows[base + tid] : -1;
    __syncthreads();
    int lane = tid & 63, wv = tid >> 6;
    int mr = lane & 15, q = lane >> 4, q8 = q * 8;
    int m0 = (wv >> 1) * 64, n0 = (wv & 1) * 64;
    int bx = blockIdx.x;

    f4 acc[4][4];
    f4 zed = {0.f, 0.f, 0.f, 0.f};
#pragma unroll
    for (int i = 0; i < 4; ++i)
#pragma unroll
        for (int j = 0; j < 4; ++j) acc[i][j] = zed;

    for (int kt = 0; kt < 8; ++kt) {
#pragma unroll
        for (int i = 0; i < 4; ++i) {
            int cch = tid + i * 256;
            int row = cch >> 3, cc = (cch & 7) * 8;
            int vr = varr[row];
            uint4 v = {0u, 0u, 0u, 0u};
            if (vr >= 0) v = *(const uint4*)(xg + (size_t)vr * 512 + kt * 64 + cc);
            *(uint4*)&As[row * 72 + cc] = v;
            uint4 wv4 = *(const uint4*)(wih2 + (size_t)(bx * 128 + row) * 512 + kt * 64 + cc);
            *(uint4*)&Bs[row * 72 + cc] = wv4;
        }
        __syncthreads();
#pragma unroll
        for (int kk = 0; kk < 64; kk += 32) {
            bf8 af[4], bgv[4];
#pragma unroll
            for (int i = 0; i < 4; ++i) af[i] = *(const bf8*)&As[(m0 + i * 16 + mr) * 72 + kk + q8];
#pragma unroll
            for (int j = 0; j < 4; ++j) bgv[j] = *(const bf8*)&Bs[(n0 + j * 16 + mr) * 72 + kk + q8];
#pragma unroll
            for (int i = 0; i < 4; ++i)
#pragma unroll
                for (int j = 0; j < 4; ++j)
                    acc[i][j] = __builtin_amdgcn_mfma_f32_16x16x32_bf16(af[i], bgv[j], acc[i][j], 0, 0, 0);
        }
        __syncthreads();
    }
#pragma unroll
    for (int j = 0; j < 4; ++j) {
        int n = bx * 128 + n0 + j * 16 + mr;
        float bias = (n < 1024) ? b_f[n] : b_b[n - 1024];
#pragma unroll
        for (int i = 0; i < 4; ++i)
#pragma unroll
            for (int r = 0; r < 4; ++r) {
                int m = m0 + i * 16 + q * 4 + r;
                int vr = varr[m];
                if (vr >= 0) xw[(size_t)vr * 2048 + n] = f2bf(acc[i][j][r] + bias);
            }
    }
}

// ---------------- fused LSTM recurrence: one kernel, all 8 steps ----------------
// Block = 4 waves, 32 spans (length-sorted slice), one direction. Wave owns a
// 64-hidden strip of all 4 gate types. Per step: preload h B-frags from LDS
// (double-buffered), stream W_hh A-frags from L2, 256 MFMAs/wave, cell math on
// accumulators. c + pooled kept in registers (~240 VGPR, no spill).
__global__ __launch_bounds__(256, 1) void lstm_fused2(const u16* __restrict__ whh2,
                                                      const u16* __restrict__ xw,
                                                      const int* __restrict__ sorder,
                                                      const int* __restrict__ lenb,
                                                      float* __restrict__ pooled) {
    __shared__ u16 Hs[2][32 * 264];
    __shared__ int sl[32], ll[32];
    int bid = blockIdx.x;
    int dir = bid >> 7, slice = bid & 127;
    int tid = threadIdx.x;
    if (tid < 32) {
        int s = sorder[slice * 32 + tid];
        sl[tid] = s;
        ll[tid] = lenb[s];
    }
    for (int i = tid; i < 2 * 32 * 264 / 2; i += 256) ((u32*)Hs)[i] = 0u;
    __syncthreads();
    int maxP = ll[0];              // sorted descending within slice
    if (maxP == 0) return;

    int wv = tid >> 6;             // wave id -> hidden strip [wv*64, wv*64+64)
    int lane = tid & 63;
    int mr = lane & 15, q = lane >> 4, q8 = q * 8;
    int w64 = wv * 64;
    const u16* wdir = whh2 + (size_t)dir * 262144;

    int spanA = sl[mr], lenA = ll[mr];
    int spanB = sl[16 + mr], lenB = ll[16 + mr];

    float c[32], pool[32];         // [gt4][st2][r4]
#pragma unroll
    for (int i = 0; i < 32; ++i) { c[i] = 0.f; pool[i] = 0.f; }

    for (int p = 0; p < maxP; ++p) {
        const u16* hread = Hs[p & 1];
        u16* hwrite = Hs[(p & 1) ^ 1];

        bf8 bg[2][8];
#pragma unroll
        for (int st = 0; st < 2; ++st)
#pragma unroll
            for (int kk = 0; kk < 8; ++kk)
                bg[st][kk] = *(const bf8*)&hread[(st * 16 + mr) * 264 + kk * 32 + q8];

        int rkA = dir ? (lenA - 1 - p) : p;  rkA = rkA < 0 ? 0 : (rkA > 7 ? 7 : rkA);
        int rkB = dir ? (lenB - 1 - p) : p;  rkB = rkB < 0 ? 0 : (rkB > 7 ? 7 : rkB);
        const u16* xwA = xw + (size_t)(spanA * 8 + rkA) * 2048 + dir * 1024;
        const u16* xwB = xw + (size_t)(spanB * 8 + rkB) * 2048 + dir * 1024;
        bool mskA = (p < lenA), mskB = (p < lenB);

#pragma unroll
        for (int gt = 0; gt < 4; ++gt) {
            f4 acc[4][2];
            f4 zed = {0.f, 0.f, 0.f, 0.f};
#pragma unroll
            for (int t = 0; t < 4; ++t) { acc[t][0] = zed; acc[t][1] = zed; }
#pragma unroll
            for (int t = 0; t < 4; ++t) {
                bf8 wf[8];
                const u16* wr = wdir + (size_t)(t * 256 + w64 + gt * 16 + mr) * 256;
#pragma unroll
                for (int kk = 0; kk < 8; ++kk)
                    wf[kk] = *(const bf8*)(wr + kk * 32 + q8);
#pragma unroll
                for (int kk = 0; kk < 8; ++kk) {
                    acc[t][0] = __builtin_amdgcn_mfma_f32_16x16x32_bf16(wf[kk], bg[0][kk], acc[t][0], 0, 0, 0);
                    acc[t][1] = __builtin_amdgcn_mfma_f32_16x16x32_bf16(wf[kk], bg[1][kk], acc[t][1], 0, 0, 0);
                }
            }
            int col = w64 + gt * 16 + q * 4;
#pragma unroll
            for (int st = 0; st < 2; ++st) {
                const u16* xwp = st ? xwB : xwA;
                bool msk = st ? mskB : mskA;
                float xv[4][4];
#pragma unroll
                for (int t = 0; t < 4; ++t) {
                    ushort4 uv = *(const ushort4*)(xwp + t * 256 + col);
                    xv[t][0] = bf2f(uv.x); xv[t][1] = bf2f(uv.y);
                    xv[t][2] = bf2f(uv.z); xv[t][3] = bf2f(uv.w);
                }
                float hv[4];
#pragma unroll
                for (int r = 0; r < 4; ++r) {
                    float I = acc[0][st][r] + xv[0][r];
                    float F = acc[1][st][r] + xv[1][r];
                    float G = acc[2][st][r] + xv[2][r];
                    float O = acc[3][st][r] + xv[3][r];
                    int ci = gt * 8 + st * 4 + r;
                    float cn = sigm(F) * c[ci] + sigm(I) * tanhf(G);
                    c[ci] = cn;
                    float h = sigm(O) * tanhf(cn);
                    hv[r] = h;
                    if (msk) pool[ci] += h;
                }
                u16* hp = &hwrite[(st * 16 + mr) * 264 + col];
                hp[0] = f2bf(hv[0]); hp[1] = f2bf(hv[1]);
                hp[2] = f2bf(hv[2]); hp[3] = f2bf(hv[3]);
            }
        }
        __syncthreads();
    }

    // final pooled store: each (span, dir-half, hidden) written by exactly one lane
#pragma unroll
    for (int gt = 0; gt < 4; ++gt)
#pragma unroll
        for (int st = 0; st < 2; ++st) {
            int span = st ? spanB : spanA;
            int col = w64 + gt * 16 + q * 4;
            float4 v;
            v.x = pool[gt * 8 + st * 4 + 0];
            v.y = pool[gt * 8 + st * 4 + 1];
            v.z = pool[gt * 8 + st * 4 + 2];
            v.w = pool[gt * 8 + st * 4 + 3];
            *(float4*)(pooled + (size_t)span * 512 + dir * 256 + col) = v;
        }
}

// ---------------- final scores: MFMA GEMM [4096x512] x [512x64] ----------------
__global__ __launch_bounds__(256) void scores_mfma(const float* __restrict__ pooled,
                                                   const float* __restrict__ emb,
                                                   float* __restrict__ out) {
    int g = blockIdx.x;
    int tid = threadIdx.x;
    __shared__ u16 As[64 * 72];
    __shared__ u16 Bs[64 * 72];
    int lane = tid & 63;
    int w16 = (tid >> 6) * 16;
    int mr = lane & 15;
    int q = lane >> 4;
    int q8 = q * 8;

    f4 acc[4];
    f4 zed = {0.f, 0.f, 0.f, 0.f};
#pragma unroll
    for (int i = 0; i < 4; ++i) acc[i] = zed;

    for (int kt = 0; kt < 8; ++kt) {
#pragma unroll
        for (int i = 0; i < 2; ++i) {
            int cch = tid + i * 256;
            int row = cch >> 3;
            int cc = (cch & 7) * 8;
            const float4* a = (const float4*)(pooled + (size_t)(g * 64 + row) * 512 + kt * 64 + cc);
            float4 v0 = a[0], v1 = a[1];
            ushort4 o0, o1;
            o0.x = f2bf(v0.x); o0.y = f2bf(v0.y); o0.z = f2bf(v0.z); o0.w = f2bf(v0.w);
            o1.x = f2bf(v1.x); o1.y = f2bf(v1.y); o1.z = f2bf(v1.z); o1.w = f2bf(v1.w);
            *(ushort4*)&As[row * 72 + cc] = o0;
            *(ushort4*)&As[row * 72 + cc + 4] = o1;
            const float4* b = (const float4*)(emb + (size_t)row * 512 + kt * 64 + cc);
            float4 w0 = b[0], w1 = b[1];
            ushort4 p0, p1;
            p0.x = f2bf(w0.x); p0.y = f2bf(w0.y); p0.z = f2bf(w0.z); p0.w = f2bf(w0.w);
            p1.x = f2bf(w1.x); p1.y = f2bf(w1.y); p1.z = f2bf(w1.z); p1.w = f2bf(w1.w);
            *(ushort4*)&Bs[row * 72 + cc] = p0;
            *(ushort4*)&Bs[row * 72 + cc + 4] = p1;
        }
        __syncthreads();
#pragma unroll
        for (int kk = 0; kk < 64; kk += 32) {
            bf8 af = *(const bf8*)&As[(w16 + mr) * 72 + kk + q8];
#pragma unroll
            for (int nt = 0; nt < 4; ++nt) {
                bf8 bgv = *(const bf8*)&Bs[(nt * 16 + mr) * 72 + kk + q8];
                acc[nt] = __builtin_amdgcn_mfma_f32_16x16x32_bf16(af, bgv, acc[nt], 0, 0, 0);
            }
        }
        __syncthreads();
    }
#pragma unroll
    for (int nt = 0; nt < 4; ++nt)
#pragma unroll
        for (int r = 0; r < 4; ++r) {
            int m = g * 64 + w16 + q * 4 + r;
            int n = nt * 16 + mr;
            out[(size_t)m * 64 + n] = acc[nt][r];
        }
}

// ---------------- launch ----------------

extern "C" void kernel_launch(void* const* d_in, const int* in_sizes, int n_in,
                              void* d_out, int out_size, void* d_ws, size_t ws_size,
                              hipStream_t stream) {
    const float* lstm_repr = (const float*)d_in[0];
    const float* W_ih_f = (const float*)d_in[1];
    const float* W_hh_f = (const float*)d_in[2];
    const float* b_f    = (const float*)d_in[3];
    const float* W_ih_b = (const float*)d_in[4];
    const float* W_hh_b = (const float*)d_in[5];
    const float* b_b    = (const float*)d_in[6];
    const float* slot_emb = (const float*)d_in[7];
    const int* bio      = (const int*)d_in[8];
    float* out = (float*)d_out;

    char* ws = (char*)d_ws;
    u16*  xg     = (u16*)(ws + 0);              // 4096*8*512 bf16   = 33,554,432
    u16*  wih2   = (u16*)(ws + 33554432);       // 2048*512 bf16     =  2,097,152
    u16*  whh2   = (u16*)(ws + 35651584);       // 2*1024*256 bf16   =  1,048,576
    int*  tok    = (int*)(ws + 36700160);       // 4096*8 i32        =    131,072
    int*  lenb   = (int*)(ws + 36831232);       // 4096 i32          =     16,384
    int*  vrows  = (int*)(ws + 36847616);       // 32768 i32         =    131,072
    int*  sorder = (int*)(ws + 36978688);       // 4096 i32          =     16,384
    int*  counts = (int*)(ws + 36995072);       // pad 256
    u16*  xw     = (u16*)(ws + 36995328);       // 32768*2048 bf16   = 134,217,728
    float* pooled= (float*)(ws + 171213056);    // 4096*512 f32      =  8,388,608 (zeroed)
    // total: 179,601,664 bytes

    build_w2<<<6144, 256, 0, stream>>>(W_ih_f, W_hh_f, W_ih_b, W_hh_b, wih2, whh2);
    pack_spans2<<<64, 512, 0, stream>>>(bio, tok, lenb);
    build_aux<<<1, 256, 0, stream>>>(lenb, vrows, sorder, counts);
    conv_gather<<<32768, 64, 0, stream>>>(lstm_repr, tok, lenb, xg);
    zero_ws<<<2048, 256, 0, stream>>>((uint4*)pooled, 524288);
    xw_gemm<<<dim3(16, 256), 256, 0, stream>>>(xg, wih2, b_f, b_b, vrows, counts, xw);
    lstm_fused2<<<256, 256, 0, stream>>>(whh2, xw, sorder, lenb, pooled);
    scores_mfma<<<64, 256, 0, stream>>>(pooled, slot_emb, out);
}